// Round 3
// baseline (2080.673 us; speedup 1.0000x reference)
//
#include <hip/hip_runtime.h>
#include <math.h>

typedef __attribute__((ext_vector_type(8))) short bf16x8;
typedef __attribute__((ext_vector_type(4))) float f32x4;

__device__ __forceinline__ float wsum64(float v) {
#pragma unroll
  for (int d = 32; d > 0; d >>= 1) v += __shfl_xor(v, d, 64);
  return v;
}

__device__ __forceinline__ unsigned spread4(unsigned x) {
  x &= 0xFFu;
  x = (x | (x << 12)) & 0x000F000Fu;
  x = (x | (x << 6)) & 0x03030303u;
  x = (x | (x << 3)) & 0x11111111u;
  return x;
}

__device__ __forceinline__ unsigned short f2bf(float f) {
  unsigned u = __float_as_uint(f);
  u = (u + 0x7FFFu + ((u >> 16) & 1u)) >> 16;
  return (unsigned short)u;
}

// per-wave LDS fence: wait own DS ops (atomics/writes) complete; no barrier.
__device__ __forceinline__ void wave_lds_fence() {
  asm volatile("s_waitcnt lgkmcnt(0)" ::: "memory");
}

// ---------------- K0: init (chadj extract + zero mean-sums) ----------------
__global__ void k_init(const float* __restrict__ smask, float* __restrict__ chadj,
                       double* __restrict__ sums) {
  int t = threadIdx.x;
  if (t < 4) sums[t] = 0.0;
  if (t < 484) {
    int c1 = t / 22, c2 = t % 22;
    chadj[t] = smask[(size_t)(c1 * 64) * 1408 + (size_t)c2 * 64];
  }
}

// ---------------- A: input GEMM: z (fp32 + bf16 + transposed) and h1-pre ----
__global__ __launch_bounds__(256) void k_gemm_in(
    const float* __restrict__ x, const float* __restrict__ projw,
    const float* __restrict__ w1, float* __restrict__ z, float* __restrict__ zT,
    unsigned short* __restrict__ zb, float* __restrict__ h1) {
  __shared__ float xs[16][68];
  __shared__ float wsT[16][68];
  __shared__ float ldsT[64][65];
  int n0 = blockIdx.x * 64;
  int o0 = blockIdx.y * 64;
  int tid = threadIdx.x;
  int tx = tid & 15, ty = tid >> 4;
  float acc[4][4];
#pragma unroll
  for (int i = 0; i < 4; i++)
#pragma unroll
    for (int j = 0; j < 4; j++) acc[i][j] = 0.f;
  for (int kc = 0; kc < 16; kc++) {
#pragma unroll
    for (int rep = 0; rep < 4; rep++) {
      int e = tid + rep * 256;
      int n = e >> 4, k = e & 15;
      xs[k][n] = x[(size_t)(n0 + n) * 256 + kc * 16 + k];
      int row = o0 + n;
      wsT[k][n] = (row < 256) ? projw[(size_t)row * 256 + kc * 16 + k]
                              : w1[(size_t)(row - 256) * 256 + kc * 16 + k];
    }
    __syncthreads();
#pragma unroll
    for (int k = 0; k < 16; k++) {
      float4 a4 = *(const float4*)&xs[k][4 * ty];
      float4 w4 = *(const float4*)&wsT[k][4 * tx];
      float ar[4] = {a4.x, a4.y, a4.z, a4.w};
      float wr[4] = {w4.x, w4.y, w4.z, w4.w};
#pragma unroll
      for (int i = 0; i < 4; i++)
#pragma unroll
        for (int j = 0; j < 4; j++) acc[i][j] = fmaf(ar[i], wr[j], acc[i][j]);
    }
    __syncthreads();
  }
  if (blockIdx.y >= 4) {
#pragma unroll
    for (int i = 0; i < 4; i++) {
      size_t base = (size_t)(n0 + 4 * ty + i) * 128 + (o0 - 256) + 4 * tx;
      float4 t;
      t.x = acc[i][0]; t.y = acc[i][1]; t.z = acc[i][2]; t.w = acc[i][3];
      *(float4*)&h1[base] = t;
    }
  } else {
#pragma unroll
    for (int i = 0; i < 4; i++) {
      size_t base = (size_t)(n0 + 4 * ty + i) * 256 + o0 + 4 * tx;
      float4 t;
      t.x = acc[i][0]; t.y = acc[i][1]; t.z = acc[i][2]; t.w = acc[i][3];
      *(float4*)&z[base] = t;
      unsigned lo = (unsigned)f2bf(acc[i][0]) | ((unsigned)f2bf(acc[i][1]) << 16);
      unsigned hi = (unsigned)f2bf(acc[i][2]) | ((unsigned)f2bf(acc[i][3]) << 16);
      uint2 u2; u2.x = lo; u2.y = hi;
      *(uint2*)(zb + base) = u2;
    }
    __syncthreads();
#pragma unroll
    for (int i = 0; i < 4; i++)
#pragma unroll
      for (int j = 0; j < 4; j++) ldsT[4 * tx + j][4 * ty + i] = acc[i][j];
    __syncthreads();
    int bblk = blockIdx.x / 22;
    int nbase = (blockIdx.x % 22) * 64;
#pragma unroll
    for (int rep = 0; rep < 16; rep++) {
      int e = tid + rep * 256;
      int oo = e >> 6, nn = e & 63;
      zT[(size_t)((bblk * 4 + blockIdx.y) * 64 + oo) * 1408 + nbase + nn] = ldsT[oo][nn];
    }
  }
}

// ---------------- B: per-node: sq per head, score (exact gelu), top-p gate --
__global__ __launch_bounds__(256) void k_node(
    const float* __restrict__ x, const float* __restrict__ z,
    const float* __restrict__ h1, const float* __restrict__ gw,
    const float* __restrict__ gb, const float* __restrict__ b1,
    const float* __restrict__ w2, const float* __restrict__ b2v,
    float* __restrict__ sq, float4* __restrict__ wnode) {
  int tid = threadIdx.x;
  int w = tid >> 6, lane = tid & 63;
  int node = blockIdx.x * 4 + w;
  int b = node / 1408, n = node % 1408;
  const float* zr = z + (size_t)node * 256;
  const float* xr = x + (size_t)node * 256;
#pragma unroll
  for (int c = 0; c < 4; c++) {
    float val = zr[c * 64 + lane];
    float s = wsum64(val * val);
    if (lane == 0) sq[(size_t)(b * 4 + c) * 1408 + n] = s;
  }
  float gl[3];
#pragma unroll
  for (int f = 0; f < 3; f++) {
    float p = 0.f;
#pragma unroll
    for (int c = 0; c < 4; c++)
      p = fmaf(xr[c * 64 + lane], gw[f * 256 + c * 64 + lane], p);
    gl[f] = wsum64(p) + gb[f];
  }
  const float* hr = h1 + (size_t)node * 128;
  float ps = 0.f;
#pragma unroll
  for (int c = 0; c < 2; c++) {
    float t = hr[c * 64 + lane] + b1[c * 64 + lane];
    float g = 0.5f * t * (1.f + erff(t * 0.7071067811865475f));
    ps = fmaf(g, w2[c * 64 + lane], ps);
  }
  float sc = wsum64(ps) + b2v[0];
  sc = 1.f / (1.f + expf(-sc));
  float mx = fmaxf(gl[0], fmaxf(gl[1], gl[2]));
  float ex[3];
  float esum = 0.f;
#pragma unroll
  for (int f = 0; f < 3; f++) { ex[f] = expf(gl[f] - mx); esum += ex[f]; }
  float p3[3];
#pragma unroll
  for (int f = 0; f < 3; f++) p3[f] = ex[f] / esum;
  int rk[3];
#pragma unroll
  for (int f = 0; f < 3; f++) {
    int r = 0;
#pragma unroll
    for (int g = 0; g < 3; g++)
      r += ((p3[g] > p3[f]) || (p3[g] == p3[f] && g < f)) ? 1 : 0;
    rk[f] = r;
  }
  float sp[3]; int oi[3];
#pragma unroll
  for (int f = 0; f < 3; f++) { sp[rk[f]] = p3[f]; oi[rk[f]] = f; }
  bool k1 = sp[0] < 0.85f;
  bool k2 = (sp[0] + sp[1]) < 0.85f;
  float wv[3];
  wv[oi[0]] = sp[0];
  wv[oi[1]] = k1 ? sp[1] : 0.f;
  wv[oi[2]] = k2 ? sp[2] : 0.f;
  float inv = 1.f / (wv[0] + wv[1] + wv[2] + 1e-8f);
  if (lane == 0) wnode[node] = make_float4(wv[0] * inv, wv[1] * inv, wv[2] * inv, sc);
}

// ---------------- P1: fp32 distances + exact top-k(211) select -> bitmap ----
// grid (88,16,4); block 256; wave w owns rows 4w..4w+3; barrier-free select.
// hist layout: bin b -> slot (b&31)*64 + (b>>5): superbin scan conflict-free.
__global__ __launch_bounds__(256, 2) void k_pass1(
    const float* __restrict__ zT, const float* __restrict__ sq,
    unsigned* __restrict__ bm, double* __restrict__ sums) {
  __shared__ float As[64][16];
  __shared__ unsigned hist[4][2048];
  __shared__ float cand[4][64];
  __shared__ unsigned candCnt[4];
  int b = blockIdx.y, h = blockIdx.z;
  int i0 = blockIdx.x * 16;
  int tid = threadIdx.x;
  int w = tid >> 6, lane = tid & 63;
  const float* zTh = zT + (size_t)((b * 4 + h) * 64) * 1408;
  const float* sqh = sq + (size_t)(b * 4 + h) * 1408;
#pragma unroll
  for (int rep = 0; rep < 4; rep++) {
    int e = tid + rep * 256;
    int k = e >> 4, r = e & 15;
    As[k][r] = zTh[(size_t)k * 1408 + i0 + r];
  }
  float srow[4];
#pragma unroll
  for (int q = 0; q < 4; q++) srow[q] = sqh[i0 + 4 * w + q];
  float v[6][4][4];
#pragma unroll
  for (int jt = 0; jt < 6; jt++)
#pragma unroll
    for (int q = 0; q < 4; q++)
#pragma unroll
      for (int cc = 0; cc < 4; cc++) v[jt][q][cc] = 0.f;
  __syncthreads();
  // FMA phase: a staged in groups of 4 k (16 regs) to avoid spill
  for (int kc = 0; kc < 4; kc++) {
#pragma unroll
    for (int g = 0; g < 4; g++) {
      float4 a4g[4];
#pragma unroll
      for (int t = 0; t < 4; t++)
        a4g[t] = *(const float4*)&As[kc * 16 + g * 4 + t][4 * w];
#pragma unroll
      for (int jt = 0; jt < 6; jt++) {
        bool vld = (jt < 5) || (lane < 32);
        const float* bp = zTh + (size_t)(kc * 16 + g * 4) * 1408 +
                          (vld ? (jt * 256 + 4 * lane) : 0);
        float4 br[4];
#pragma unroll
        for (int t = 0; t < 4; t++)
          br[t] = *(const float4*)(bp + (size_t)t * 1408);
#pragma unroll
        for (int t = 0; t < 4; t++) {
          float ar[4] = {a4g[t].x, a4g[t].y, a4g[t].z, a4g[t].w};
          float brr[4] = {br[t].x, br[t].y, br[t].z, br[t].w};
#pragma unroll
          for (int q = 0; q < 4; q++)
#pragma unroll
            for (int cc = 0; cc < 4; cc++)
              v[jt][q][cc] = fmaf(ar[q], brr[cc], v[jt][q][cc]);
        }
      }
    }
  }
  // finalize dot -> clamped d^2 (invalid -> +inf); accumulate sum sqrt
  float ssum = 0.f;
#pragma unroll
  for (int jt = 0; jt < 6; jt++) {
    bool vld = (jt < 5) || (lane < 32);
    float4 s4 = *(const float4*)(sqh + (vld ? (jt * 256 + 4 * lane) : 0));
    float sb[4] = {s4.x, s4.y, s4.z, s4.w};
#pragma unroll
    for (int q = 0; q < 4; q++)
#pragma unroll
      for (int cc = 0; cc < 4; cc++) {
        float d = srow[q] + sb[cc] - 2.f * v[jt][q][cc];
        d = fmaxf(d, 0.f);
        if (vld) ssum += sqrtf(d);
        v[jt][q][cc] = vld ? d : INFINITY;
      }
  }
  // per-row exact rank-211 selection (per-wave private; no block barriers)
#pragma unroll 1
  for (int q = 0; q < 4; q++) {
    uint4 z4 = {0u, 0u, 0u, 0u};
    uint4* hp = (uint4*)&hist[w][0];
#pragma unroll
    for (int i = 0; i < 8; i++) hp[i * 64 + lane] = z4;
    if (lane == 0) candCnt[w] = 0u;
    wave_lds_fence();
#pragma unroll
    for (int jt = 0; jt < 6; jt++) {
      bool vld = (jt < 5) || (lane < 32);
      if (vld) {
#pragma unroll
        for (int cc = 0; cc < 4; cc++) {
          unsigned key = (unsigned)fminf(v[jt][q][cc] * 16.0f, 2047.0f);
          atomicAdd(&hist[w][(key & 31u) * 64u + (key >> 5)], 1u);
        }
      }
    }
    wave_lds_fence();
    // superbin sums: lane L = bins [32L,32L+32): slots j*64+L (conflict-free)
    unsigned ssb = 0;
#pragma unroll
    for (int j = 0; j < 32; j++) ssb += hist[w][j * 64 + lane];
    unsigned inc = ssb;
#pragma unroll
    for (int d = 1; d < 64; d <<= 1) {
      unsigned u = __shfl_up(inc, d, 64);
      if (lane >= d) inc += u;
    }
    unsigned long long mk = __ballot(inc >= 211u);
    int Ls = __ffsll(mk) - 1;
    unsigned cbefore = (Ls > 0) ? (unsigned)__shfl((int)inc, Ls - 1, 64) : 0u;
    // refine within superbin Ls: lane i<32 reads bin 32*Ls+i at slot i*64+Ls
    unsigned v2 = (lane < 32) ? hist[w][lane * 64 + Ls] : 0u;
    unsigned inc2 = v2;
#pragma unroll
    for (int d = 1; d < 32; d <<= 1) {
      unsigned u = __shfl_up(inc2, d, 64);
      if (lane >= d) inc2 += u;
    }
    bool c2 = (lane < 32) && (cbefore + inc2 >= 211u);
    mk = __ballot(c2);
    int is = __ffsll(mk) - 1;
    unsigned cbelow = cbefore + ((is > 0) ? (unsigned)__shfl((int)inc2, is - 1, 64) : 0u);
    int rstar = 211 - (int)cbelow;
    int tbin = Ls * 32 + is;
    // collect boundary-bin candidates
#pragma unroll
    for (int jt = 0; jt < 6; jt++) {
      bool vld = (jt < 5) || (lane < 32);
      if (vld) {
#pragma unroll
        for (int cc = 0; cc < 4; cc++) {
          float val = v[jt][q][cc];
          unsigned key = (unsigned)fminf(val * 16.0f, 2047.0f);
          if ((int)key == tbin) {
            unsigned id = atomicAdd(&candCnt[w], 1u);
            if (id < 64u) cand[w][id] = val;
          }
        }
      }
    }
    wave_lds_fence();
    unsigned craw = candCnt[w];
    int cnt = (craw > 64u) ? 64 : (int)craw;
    float t2l = INFINITY;
    if (lane < cnt) {
      float xm = cand[w][lane];
      int below = 0, eq = 0;
      for (int m = 0; m < cnt; m++) {
        float y = cand[w][m];
        below += (y < xm) ? 1 : 0;
        eq += (y == xm) ? 1 : 0;
      }
      if (below < rstar && rstar <= below + eq) t2l = xm;
    }
#pragma unroll
    for (int dd = 32; dd > 0; dd >>= 1) t2l = fminf(t2l, __shfl_xor(t2l, dd, 64));
    float T = t2l;
    // bitmap
    int row = i0 + 4 * w + q;
    unsigned* bmrow = bm + (size_t)((h * 16 + b) * 1408 + row) * 44;
#pragma unroll
    for (int jt = 0; jt < 6; jt++) {
      unsigned long long bl[4];
#pragma unroll
      for (int cc = 0; cc < 4; cc++) {
        bool vld = (jt < 5) || (lane < 32);
        bl[cc] = __ballot((vld && v[jt][q][cc] <= T) ? 1 : 0);
      }
      if (lane < 8) {
        int wid = jt * 8 + lane;
        if (wid < 44) {
          unsigned word = 0;
#pragma unroll
          for (int cc = 0; cc < 4; cc++) {
            unsigned byt = (unsigned)((bl[cc] >> (8 * lane)) & 0xFFull);
            word |= spread4(byt) << cc;
          }
          bmrow[wid] = word;
        }
      }
    }
    wave_lds_fence();  // hist reuse next row: ensure reads done before re-zero
  }
  ssum = wsum64(ssum);
  if (lane == 0) atomicAdd(&sums[h], (double)ssum);
}

// ---------------- E: bf16-MFMA recompute + fused epilogue -> out ------------
__global__ __launch_bounds__(256) void k_final(
    const unsigned short* __restrict__ zb, const float* __restrict__ sq,
    const float4* __restrict__ wnode, const unsigned* __restrict__ bm,
    const double* __restrict__ sums, const float* __restrict__ chadj,
    const float* __restrict__ thrp, float* __restrict__ out) {
  int it = blockIdx.x, jt = blockIdx.y, b = blockIdx.z;
  int tid = threadIdx.x, wv = tid >> 6, lane = tid & 63;
  int quad = lane >> 4, l15 = lane & 15;
  float c2h[4];
#pragma unroll
  for (int h = 0; h < 4; h++) {
    double mu = sums[h] * (1.0 / (16.0 * 1408.0 * 1408.0));
    c2h[h] = (float)(1.0 / (2.0 * mu * mu + 1e-8)) * 1.44269504088896f;
  }
  float thr = thrp[0];
  int ib = it * 64 + wv * 16;
  const unsigned short* za = zb + (size_t)(b * 1408 + ib + l15) * 256;
  bf16x8 af[4][2];
#pragma unroll
  for (int h = 0; h < 4; h++)
#pragma unroll
    for (int k0 = 0; k0 < 2; k0++)
      af[h][k0] = *(const bf16x8*)(za + h * 64 + k0 * 32 + quad * 8);
  int ibq = ib + quad * 4;
  float4 wi[4];
  float sqi[4][4];
#pragma unroll
  for (int reg = 0; reg < 4; reg++) {
    int i = ibq + reg;
    wi[reg] = wnode[b * 1408 + i];
#pragma unroll
    for (int h = 0; h < 4; h++) sqi[reg][h] = sq[(size_t)(b * 4 + h) * 1408 + i];
  }
#pragma unroll
  for (int js = 0; js < 4; js++) {
    int j = jt * 64 + js * 16 + l15;
    const unsigned short* zj = zb + (size_t)(b * 1408 + j) * 256;
    f32x4 acc[4];
#pragma unroll
    for (int h = 0; h < 4; h++) {
      bf16x8 b0 = *(const bf16x8*)(zj + h * 64 + quad * 8);
      bf16x8 b1f = *(const bf16x8*)(zj + h * 64 + 32 + quad * 8);
      f32x4 a = {0.f, 0.f, 0.f, 0.f};
      a = __builtin_amdgcn_mfma_f32_16x16x32_bf16(af[h][0], b0, a, 0, 0, 0);
      a = __builtin_amdgcn_mfma_f32_16x16x32_bf16(af[h][1], b1f, a, 0, 0, 0);
      acc[h] = a;
    }
    float sqj[4];
#pragma unroll
    for (int h = 0; h < 4; h++) sqj[h] = sq[(size_t)(b * 4 + h) * 1408 + j];
    float4 wj = wnode[b * 1408 + j];
    float adjv[4] = {0.f, 0.f, 0.f, 0.f};
#pragma unroll
    for (int h = 0; h < 4; h++) {
      const unsigned* bmh = bm + (size_t)(h * 16 + b) * 1408 * 44;
      unsigned wJ = bmh[(size_t)j * 44 + (ibq >> 5)];
#pragma unroll
      for (int reg = 0; reg < 4; reg++) {
        int i = ibq + reg;
        float d2 = sqi[reg][h] + sqj[h] - 2.f * acc[h][reg];
        d2 = fmaxf(d2, 0.f);
        float sim = exp2f(-d2 * c2h[h]);
        unsigned bi = bmh[(size_t)i * 44 + (j >> 5)] >> (j & 31);
        unsigned bj = wJ >> (i & 31);
        adjv[reg] += (((bi | bj) & 1u) != 0u) ? sim : 0.f;
      }
    }
#pragma unroll
    for (int reg = 0; reg < 4; reg++) {
      int i = ibq + reg;
      int chi = i >> 6, pi = i & 63, chj = j >> 6, pj = j & 63;
      float e0 = 0.5f * (wi[reg].x + wj.x);
      float e1 = 0.5f * (wi[reg].y + wj.y);
      float e2 = 0.5f * (wi[reg].z + wj.z);
      float a2 = 0.f;
      if (chi == chj) {
        int dp = pi - pj;
        if (dp == 1 || dp == -1) a2 += e0;
      }
      if (pi == pj && chadj[chi * 22 + chj] != 0.f) a2 += e1;
      float xw = (wi[reg].w * wj.w - thr) * 10.f;
      float pt = 1.f / (1.f + exp2f(-xw * 1.44269504088896f));
      a2 += pt * e2;
      out[(size_t)(b * 1408 + i) * 1408 + j] = 0.25f * adjv[reg] * a2;
    }
  }
}

// ---------------------------------------------------------------------------
extern "C" void kernel_launch(void* const* d_in, const int* in_sizes, int n_in,
                              void* d_out, int out_size, void* d_ws, size_t ws_size,
                              hipStream_t stream) {
  (void)in_sizes; (void)n_in; (void)out_size; (void)ws_size;
  const float* x = (const float*)d_in[0];
  const float* projw = (const float*)d_in[1];
  const float* gw = (const float*)d_in[2];
  const float* gb = (const float*)d_in[3];
  const float* w1 = (const float*)d_in[4];
  const float* b1 = (const float*)d_in[5];
  const float* w2 = (const float*)d_in[6];
  const float* b2 = (const float*)d_in[7];
  const float* thr = (const float*)d_in[8];
  const float* smask = (const float*)d_in[10];
  float* out = (float*)d_out;
  char* ws = (char*)d_ws;
  size_t off = 0;
  auto take = [&](size_t bytes) {
    char* p = ws + off;
    off += (bytes + 255) & ~(size_t)255;
    return p;
  };
  float* z = (float*)take((size_t)22528 * 256 * 4);
  float* zT = (float*)take((size_t)22528 * 256 * 4);
  unsigned short* zb = (unsigned short*)take((size_t)22528 * 256 * 2);
  float* h1 = (float*)take((size_t)22528 * 128 * 4);
  float* sq = (float*)take((size_t)16 * 4 * 1408 * 4);
  float4* wnode = (float4*)take((size_t)22528 * 16);
  unsigned* bm = (unsigned*)take((size_t)4 * 16 * 1408 * 44 * 4);
  float* chadj = (float*)take(484 * 4);
  double* sums = (double*)take(4 * 8);

  hipLaunchKernelGGL(k_init, dim3(1), dim3(512), 0, stream, smask, chadj, sums);
  hipLaunchKernelGGL(k_gemm_in, dim3(352, 6), dim3(256), 0, stream, x, projw, w1,
                     z, zT, zb, h1);
  hipLaunchKernelGGL(k_node, dim3(5632), dim3(256), 0, stream, x, z, h1, gw, gb,
                     b1, w2, b2, sq, wnode);
  hipLaunchKernelGGL(k_pass1, dim3(88, 16, 4), dim3(256), 0, stream, zT, sq, bm,
                     sums);
  hipLaunchKernelGGL(k_final, dim3(22, 22, 16), dim3(256), 0, stream, zb, sq,
                     wnode, bm, sums, chadj, thr, out);
}

// Round 4
// 1379.971 us; speedup vs baseline: 1.5078x; 1.5078x over previous
//
#include <hip/hip_runtime.h>
#include <math.h>

typedef __attribute__((ext_vector_type(8))) short bf16x8;
typedef __attribute__((ext_vector_type(4))) float f32x4;

__device__ __forceinline__ float wsum64(float v) {
#pragma unroll
  for (int d = 32; d > 0; d >>= 1) v += __shfl_xor(v, d, 64);
  return v;
}

__device__ __forceinline__ unsigned spread4(unsigned x) {
  x &= 0xFFu;
  x = (x | (x << 12)) & 0x000F000Fu;
  x = (x | (x << 6)) & 0x03030303u;
  x = (x | (x << 3)) & 0x11111111u;
  return x;
}

__device__ __forceinline__ unsigned short f2bf(float f) {
  unsigned u = __float_as_uint(f);
  u = (u + 0x7FFFu + ((u >> 16) & 1u)) >> 16;
  return (unsigned short)u;
}

// per-wave LDS fence: wait own DS ops complete; no block barrier.
__device__ __forceinline__ void wave_lds_fence() {
  asm volatile("s_waitcnt lgkmcnt(0)" ::: "memory");
}

// ---------------- K0: init (chadj extract + zero mean-sums) ----------------
__global__ void k_init(const float* __restrict__ smask, float* __restrict__ chadj,
                       double* __restrict__ sums) {
  int t = threadIdx.x;
  if (t < 4) sums[t] = 0.0;
  if (t < 484) {
    int c1 = t / 22, c2 = t % 22;
    chadj[t] = smask[(size_t)(c1 * 64) * 1408 + (size_t)c2 * 64];
  }
}

// ---------------- A: input GEMM: z (fp32 + bf16 + transposed) and h1-pre ----
__global__ __launch_bounds__(256) void k_gemm_in(
    const float* __restrict__ x, const float* __restrict__ projw,
    const float* __restrict__ w1, float* __restrict__ z, float* __restrict__ zT,
    unsigned short* __restrict__ zb, float* __restrict__ h1) {
  __shared__ float xs[16][68];
  __shared__ float wsT[16][68];
  __shared__ float ldsT[64][65];
  int n0 = blockIdx.x * 64;
  int o0 = blockIdx.y * 64;
  int tid = threadIdx.x;
  int tx = tid & 15, ty = tid >> 4;
  float acc[4][4];
#pragma unroll
  for (int i = 0; i < 4; i++)
#pragma unroll
    for (int j = 0; j < 4; j++) acc[i][j] = 0.f;
  for (int kc = 0; kc < 16; kc++) {
#pragma unroll
    for (int rep = 0; rep < 4; rep++) {
      int e = tid + rep * 256;
      int n = e >> 4, k = e & 15;
      xs[k][n] = x[(size_t)(n0 + n) * 256 + kc * 16 + k];
      int row = o0 + n;
      wsT[k][n] = (row < 256) ? projw[(size_t)row * 256 + kc * 16 + k]
                              : w1[(size_t)(row - 256) * 256 + kc * 16 + k];
    }
    __syncthreads();
#pragma unroll
    for (int k = 0; k < 16; k++) {
      float4 a4 = *(const float4*)&xs[k][4 * ty];
      float4 w4 = *(const float4*)&wsT[k][4 * tx];
      float ar[4] = {a4.x, a4.y, a4.z, a4.w};
      float wr[4] = {w4.x, w4.y, w4.z, w4.w};
#pragma unroll
      for (int i = 0; i < 4; i++)
#pragma unroll
        for (int j = 0; j < 4; j++) acc[i][j] = fmaf(ar[i], wr[j], acc[i][j]);
    }
    __syncthreads();
  }
  if (blockIdx.y >= 4) {
#pragma unroll
    for (int i = 0; i < 4; i++) {
      size_t base = (size_t)(n0 + 4 * ty + i) * 128 + (o0 - 256) + 4 * tx;
      float4 t;
      t.x = acc[i][0]; t.y = acc[i][1]; t.z = acc[i][2]; t.w = acc[i][3];
      *(float4*)&h1[base] = t;
    }
  } else {
#pragma unroll
    for (int i = 0; i < 4; i++) {
      size_t base = (size_t)(n0 + 4 * ty + i) * 256 + o0 + 4 * tx;
      float4 t;
      t.x = acc[i][0]; t.y = acc[i][1]; t.z = acc[i][2]; t.w = acc[i][3];
      *(float4*)&z[base] = t;
      unsigned lo = (unsigned)f2bf(acc[i][0]) | ((unsigned)f2bf(acc[i][1]) << 16);
      unsigned hi = (unsigned)f2bf(acc[i][2]) | ((unsigned)f2bf(acc[i][3]) << 16);
      uint2 u2; u2.x = lo; u2.y = hi;
      *(uint2*)(zb + base) = u2;
    }
    __syncthreads();
#pragma unroll
    for (int i = 0; i < 4; i++)
#pragma unroll
      for (int j = 0; j < 4; j++) ldsT[4 * tx + j][4 * ty + i] = acc[i][j];
    __syncthreads();
    int bblk = blockIdx.x / 22;
    int nbase = (blockIdx.x % 22) * 64;
#pragma unroll
    for (int rep = 0; rep < 16; rep++) {
      int e = tid + rep * 256;
      int oo = e >> 6, nn = e & 63;
      zT[(size_t)((bblk * 4 + blockIdx.y) * 64 + oo) * 1408 + nbase + nn] = ldsT[oo][nn];
    }
  }
}

// ---------------- B: per-node: sq per head, score (exact gelu), top-p gate --
__global__ __launch_bounds__(256) void k_node(
    const float* __restrict__ x, const float* __restrict__ z,
    const float* __restrict__ h1, const float* __restrict__ gw,
    const float* __restrict__ gb, const float* __restrict__ b1,
    const float* __restrict__ w2, const float* __restrict__ b2v,
    float* __restrict__ sq, float4* __restrict__ wnode) {
  int tid = threadIdx.x;
  int w = tid >> 6, lane = tid & 63;
  int node = blockIdx.x * 4 + w;
  int b = node / 1408, n = node % 1408;
  const float* zr = z + (size_t)node * 256;
  const float* xr = x + (size_t)node * 256;
#pragma unroll
  for (int c = 0; c < 4; c++) {
    float val = zr[c * 64 + lane];
    float s = wsum64(val * val);
    if (lane == 0) sq[(size_t)(b * 4 + c) * 1408 + n] = s;
  }
  float gl[3];
#pragma unroll
  for (int f = 0; f < 3; f++) {
    float p = 0.f;
#pragma unroll
    for (int c = 0; c < 4; c++)
      p = fmaf(xr[c * 64 + lane], gw[f * 256 + c * 64 + lane], p);
    gl[f] = wsum64(p) + gb[f];
  }
  const float* hr = h1 + (size_t)node * 128;
  float ps = 0.f;
#pragma unroll
  for (int c = 0; c < 2; c++) {
    float t = hr[c * 64 + lane] + b1[c * 64 + lane];
    float g = 0.5f * t * (1.f + erff(t * 0.7071067811865475f));
    ps = fmaf(g, w2[c * 64 + lane], ps);
  }
  float sc = wsum64(ps) + b2v[0];
  sc = 1.f / (1.f + expf(-sc));
  float mx = fmaxf(gl[0], fmaxf(gl[1], gl[2]));
  float ex[3];
  float esum = 0.f;
#pragma unroll
  for (int f = 0; f < 3; f++) { ex[f] = expf(gl[f] - mx); esum += ex[f]; }
  float p3[3];
#pragma unroll
  for (int f = 0; f < 3; f++) p3[f] = ex[f] / esum;
  int rk[3];
#pragma unroll
  for (int f = 0; f < 3; f++) {
    int r = 0;
#pragma unroll
    for (int g = 0; g < 3; g++)
      r += ((p3[g] > p3[f]) || (p3[g] == p3[f] && g < f)) ? 1 : 0;
    rk[f] = r;
  }
  float sp[3]; int oi[3];
#pragma unroll
  for (int f = 0; f < 3; f++) { sp[rk[f]] = p3[f]; oi[rk[f]] = f; }
  bool k1 = sp[0] < 0.85f;
  bool k2 = (sp[0] + sp[1]) < 0.85f;
  float wv[3];
  wv[oi[0]] = sp[0];
  wv[oi[1]] = k1 ? sp[1] : 0.f;
  wv[oi[2]] = k2 ? sp[2] : 0.f;
  float inv = 1.f / (wv[0] + wv[1] + wv[2] + 1e-8f);
  if (lane == 0) wnode[node] = make_float4(wv[0] * inv, wv[1] * inv, wv[2] * inv, sc);
}

// ---------------- P1: fp32 distances + exact top-k(211) select -> bitmap ----
// grid (88,16,4); block 256; wave w owns rows 4w..4w+3.
// hist slot(b) = b + (b>>5) (stride-33 padding): scan & refine conflict-free.
// All select state is wave-private: no block barriers in the select.
__global__ __launch_bounds__(256, 2) void k_pass1(
    const float* __restrict__ zT, const float* __restrict__ sq,
    unsigned* __restrict__ bm, double* __restrict__ sums) {
  __shared__ float As[64][16];
  __shared__ unsigned hist[4][2112];
  __shared__ float cand[4][64];
  __shared__ unsigned candCnt[4];
  int b = blockIdx.y, h = blockIdx.z;
  int i0 = blockIdx.x * 16;
  int tid = threadIdx.x;
  int w = tid >> 6, lane = tid & 63;
  const float* zTh = zT + (size_t)((b * 4 + h) * 64) * 1408;
  const float* sqh = sq + (size_t)(b * 4 + h) * 1408;
#pragma unroll
  for (int rep = 0; rep < 4; rep++) {
    int e = tid + rep * 256;
    int k = e >> 4, r = e & 15;
    As[k][r] = zTh[(size_t)k * 1408 + i0 + r];
  }
  float srow[4];
#pragma unroll
  for (int q = 0; q < 4; q++) srow[q] = sqh[i0 + 4 * w + q];
  float v[6][4][4];
#pragma unroll
  for (int jt = 0; jt < 6; jt++)
#pragma unroll
    for (int q = 0; q < 4; q++)
#pragma unroll
      for (int cc = 0; cc < 4; cc++) v[jt][q][cc] = 0.f;
  __syncthreads();
  // FMA phase: A staged in groups of 4 k (16 regs) to avoid spill
  for (int kc = 0; kc < 4; kc++) {
#pragma unroll
    for (int g = 0; g < 4; g++) {
      float4 a4g[4];
#pragma unroll
      for (int t = 0; t < 4; t++)
        a4g[t] = *(const float4*)&As[kc * 16 + g * 4 + t][4 * w];
#pragma unroll
      for (int jt = 0; jt < 6; jt++) {
        bool vld = (jt < 5) || (lane < 32);
        const float* bp = zTh + (size_t)(kc * 16 + g * 4) * 1408 +
                          (vld ? (jt * 256 + 4 * lane) : 0);
        float4 br[4];
#pragma unroll
        for (int t = 0; t < 4; t++)
          br[t] = *(const float4*)(bp + (size_t)t * 1408);
#pragma unroll
        for (int t = 0; t < 4; t++) {
          float ar[4] = {a4g[t].x, a4g[t].y, a4g[t].z, a4g[t].w};
          float brr[4] = {br[t].x, br[t].y, br[t].z, br[t].w};
#pragma unroll
          for (int q = 0; q < 4; q++)
#pragma unroll
            for (int cc = 0; cc < 4; cc++)
              v[jt][q][cc] = fmaf(ar[q], brr[cc], v[jt][q][cc]);
        }
      }
    }
  }
  // finalize dot -> clamped d^2 (invalid -> +inf); accumulate sum sqrt
  float ssum = 0.f;
#pragma unroll
  for (int jt = 0; jt < 6; jt++) {
    bool vld = (jt < 5) || (lane < 32);
    float4 s4 = *(const float4*)(sqh + (vld ? (jt * 256 + 4 * lane) : 0));
    float sb[4] = {s4.x, s4.y, s4.z, s4.w};
#pragma unroll
    for (int q = 0; q < 4; q++)
#pragma unroll
      for (int cc = 0; cc < 4; cc++) {
        float d = srow[q] + sb[cc] - 2.f * v[jt][q][cc];
        d = fmaxf(d, 0.f);
        if (vld) ssum += sqrtf(d);
        v[jt][q][cc] = vld ? d : INFINITY;
      }
  }
  // per-row exact rank-211 selection (per-wave private; FULLY UNROLLED so the
  // v[][][] array stays register-resident -- dynamic indexing spills it)
#pragma unroll
  for (int q = 0; q < 4; q++) {
    // zero hist: stride-64 stores, bank = lane&31 -> 2-way (free)
#pragma unroll
    for (int t = 0; t < 33; t++) hist[w][t * 64 + lane] = 0u;
    if (lane == 0) candCnt[w] = 0u;
    wave_lds_fence();
    // fill
#pragma unroll
    for (int jt = 0; jt < 6; jt++) {
      bool vld = (jt < 5) || (lane < 32);
      if (vld) {
#pragma unroll
        for (int cc = 0; cc < 4; cc++) {
          unsigned key = (unsigned)fminf(v[jt][q][cc] * 16.0f, 2047.0f);
          atomicAdd(&hist[w][key + (key >> 5)], 1u);
        }
      }
    }
    wave_lds_fence();
    // superbin sums: lane L sums bins [32L,32L+32) at 33L+t -> bank (L+t)&31
    unsigned ssb = 0;
    int sbase = 33 * lane;
#pragma unroll
    for (int t = 0; t < 32; t++) ssb += hist[w][sbase + t];
    unsigned inc = ssb;
#pragma unroll
    for (int d = 1; d < 64; d <<= 1) {
      unsigned u = __shfl_up(inc, d, 64);
      if (lane >= d) inc += u;
    }
    unsigned long long mk = __ballot(inc >= 211u);
    int Ls = __ffsll(mk) - 1;
    unsigned cbefore = (Ls > 0) ? (unsigned)__shfl((int)inc, Ls - 1, 64) : 0u;
    // refine in superbin Ls: lane i<32 reads bin 32Ls+i at 33Ls+i (no confl.)
    unsigned v2 = (lane < 32) ? hist[w][33 * Ls + lane] : 0u;
    unsigned inc2 = v2;
#pragma unroll
    for (int d = 1; d < 32; d <<= 1) {
      unsigned u = __shfl_up(inc2, d, 64);
      if (lane >= d) inc2 += u;
    }
    bool c2 = (lane < 32) && (cbefore + inc2 >= 211u);
    mk = __ballot(c2);
    int is = __ffsll(mk) - 1;
    unsigned cbelow = cbefore + ((is > 0) ? (unsigned)__shfl((int)inc2, is - 1, 64) : 0u);
    int rstar = 211 - (int)cbelow;
    int tbin = Ls * 32 + is;
    // collect boundary-bin candidates
#pragma unroll
    for (int jt = 0; jt < 6; jt++) {
      bool vld = (jt < 5) || (lane < 32);
      if (vld) {
#pragma unroll
        for (int cc = 0; cc < 4; cc++) {
          float val = v[jt][q][cc];
          unsigned key = (unsigned)fminf(val * 16.0f, 2047.0f);
          if ((int)key == tbin) {
            unsigned id = atomicAdd(&candCnt[w], 1u);
            if (id < 64u) cand[w][id] = val;
          }
        }
      }
    }
    wave_lds_fence();
    unsigned craw = candCnt[w];
    int cnt = (craw > 64u) ? 64 : (int)craw;
    float t2l = INFINITY;
    if (lane < cnt) {
      float xm = cand[w][lane];
      int below = 0, eq = 0;
      for (int m = 0; m < cnt; m++) {
        float y = cand[w][m];
        below += (y < xm) ? 1 : 0;
        eq += (y == xm) ? 1 : 0;
      }
      if (below < rstar && rstar <= below + eq) t2l = xm;
    }
#pragma unroll
    for (int dd = 32; dd > 0; dd >>= 1) t2l = fminf(t2l, __shfl_xor(t2l, dd, 64));
    float T = t2l;
    // bitmap
    int row = i0 + 4 * w + q;
    unsigned* bmrow = bm + (size_t)((h * 16 + b) * 1408 + row) * 44;
#pragma unroll
    for (int jt = 0; jt < 6; jt++) {
      unsigned long long bl[4];
#pragma unroll
      for (int cc = 0; cc < 4; cc++) {
        bool vld = (jt < 5) || (lane < 32);
        bl[cc] = __ballot((vld && v[jt][q][cc] <= T) ? 1 : 0);
      }
      if (lane < 8) {
        int wid = jt * 8 + lane;
        if (wid < 44) {
          unsigned word = 0;
#pragma unroll
          for (int cc = 0; cc < 4; cc++) {
            unsigned byt = (unsigned)((bl[cc] >> (8 * lane)) & 0xFFull);
            word |= spread4(byt) << cc;
          }
          bmrow[wid] = word;
        }
      }
    }
    wave_lds_fence();
  }
  ssum = wsum64(ssum);
  if (lane == 0) atomicAdd(&sums[h], (double)ssum);
}

// ---------------- E: bf16-MFMA recompute + fused epilogue -> out ------------
__global__ __launch_bounds__(256) void k_final(
    const unsigned short* __restrict__ zb, const float* __restrict__ sq,
    const float4* __restrict__ wnode, const unsigned* __restrict__ bm,
    const double* __restrict__ sums, const float* __restrict__ chadj,
    const float* __restrict__ thrp, float* __restrict__ out) {
  int it = blockIdx.x, jt = blockIdx.y, b = blockIdx.z;
  int tid = threadIdx.x, wv = tid >> 6, lane = tid & 63;
  int quad = lane >> 4, l15 = lane & 15;
  float c2h[4];
#pragma unroll
  for (int h = 0; h < 4; h++) {
    double mu = sums[h] * (1.0 / (16.0 * 1408.0 * 1408.0));
    c2h[h] = (float)(1.0 / (2.0 * mu * mu + 1e-8)) * 1.44269504088896f;
  }
  float thr = thrp[0];
  int ib = it * 64 + wv * 16;
  const unsigned short* za = zb + (size_t)(b * 1408 + ib + l15) * 256;
  bf16x8 af[4][2];
#pragma unroll
  for (int h = 0; h < 4; h++)
#pragma unroll
    for (int k0 = 0; k0 < 2; k0++)
      af[h][k0] = *(const bf16x8*)(za + h * 64 + k0 * 32 + quad * 8);
  int ibq = ib + quad * 4;
  float4 wi[4];
  float sqi[4][4];
#pragma unroll
  for (int reg = 0; reg < 4; reg++) {
    int i = ibq + reg;
    wi[reg] = wnode[b * 1408 + i];
#pragma unroll
    for (int h = 0; h < 4; h++) sqi[reg][h] = sq[(size_t)(b * 4 + h) * 1408 + i];
  }
#pragma unroll
  for (int js = 0; js < 4; js++) {
    int j = jt * 64 + js * 16 + l15;
    const unsigned short* zj = zb + (size_t)(b * 1408 + j) * 256;
    f32x4 acc[4];
#pragma unroll
    for (int h = 0; h < 4; h++) {
      bf16x8 b0 = *(const bf16x8*)(zj + h * 64 + quad * 8);
      bf16x8 b1f = *(const bf16x8*)(zj + h * 64 + 32 + quad * 8);
      f32x4 a = {0.f, 0.f, 0.f, 0.f};
      a = __builtin_amdgcn_mfma_f32_16x16x32_bf16(af[h][0], b0, a, 0, 0, 0);
      a = __builtin_amdgcn_mfma_f32_16x16x32_bf16(af[h][1], b1f, a, 0, 0, 0);
      acc[h] = a;
    }
    float sqj[4];
#pragma unroll
    for (int h = 0; h < 4; h++) sqj[h] = sq[(size_t)(b * 4 + h) * 1408 + j];
    float4 wj = wnode[b * 1408 + j];
    float adjv[4] = {0.f, 0.f, 0.f, 0.f};
#pragma unroll
    for (int h = 0; h < 4; h++) {
      const unsigned* bmh = bm + (size_t)(h * 16 + b) * 1408 * 44;
      unsigned wJ = bmh[(size_t)j * 44 + (ibq >> 5)];
#pragma unroll
      for (int reg = 0; reg < 4; reg++) {
        int i = ibq + reg;
        float d2 = sqi[reg][h] + sqj[h] - 2.f * acc[h][reg];
        d2 = fmaxf(d2, 0.f);
        float sim = exp2f(-d2 * c2h[h]);
        unsigned bi = bmh[(size_t)i * 44 + (j >> 5)] >> (j & 31);
        unsigned bj = wJ >> (i & 31);
        adjv[reg] += (((bi | bj) & 1u) != 0u) ? sim : 0.f;
      }
    }
#pragma unroll
    for (int reg = 0; reg < 4; reg++) {
      int i = ibq + reg;
      int chi = i >> 6, pi = i & 63, chj = j >> 6, pj = j & 63;
      float e0 = 0.5f * (wi[reg].x + wj.x);
      float e1 = 0.5f * (wi[reg].y + wj.y);
      float e2 = 0.5f * (wi[reg].z + wj.z);
      float a2 = 0.f;
      if (chi == chj) {
        int dp = pi - pj;
        if (dp == 1 || dp == -1) a2 += e0;
      }
      if (pi == pj && chadj[chi * 22 + chj] != 0.f) a2 += e1;
      float xw = (wi[reg].w * wj.w - thr) * 10.f;
      float pt = 1.f / (1.f + exp2f(-xw * 1.44269504088896f));
      a2 += pt * e2;
      out[(size_t)(b * 1408 + i) * 1408 + j] = 0.25f * adjv[reg] * a2;
    }
  }
}

// ---------------------------------------------------------------------------
extern "C" void kernel_launch(void* const* d_in, const int* in_sizes, int n_in,
                              void* d_out, int out_size, void* d_ws, size_t ws_size,
                              hipStream_t stream) {
  (void)in_sizes; (void)n_in; (void)out_size; (void)ws_size;
  const float* x = (const float*)d_in[0];
  const float* projw = (const float*)d_in[1];
  const float* gw = (const float*)d_in[2];
  const float* gb = (const float*)d_in[3];
  const float* w1 = (const float*)d_in[4];
  const float* b1 = (const float*)d_in[5];
  const float* w2 = (const float*)d_in[6];
  const float* b2 = (const float*)d_in[7];
  const float* thr = (const float*)d_in[8];
  const float* smask = (const float*)d_in[10];
  float* out = (float*)d_out;
  char* ws = (char*)d_ws;
  size_t off = 0;
  auto take = [&](size_t bytes) {
    char* p = ws + off;
    off += (bytes + 255) & ~(size_t)255;
    return p;
  };
  float* z = (float*)take((size_t)22528 * 256 * 4);
  float* zT = (float*)take((size_t)22528 * 256 * 4);
  unsigned short* zb = (unsigned short*)take((size_t)22528 * 256 * 2);
  float* h1 = (float*)take((size_t)22528 * 128 * 4);
  float* sq = (float*)take((size_t)16 * 4 * 1408 * 4);
  float4* wnode = (float4*)take((size_t)22528 * 16);
  unsigned* bm = (unsigned*)take((size_t)4 * 16 * 1408 * 44 * 4);
  float* chadj = (float*)take(484 * 4);
  double* sums = (double*)take(4 * 8);

  hipLaunchKernelGGL(k_init, dim3(1), dim3(512), 0, stream, smask, chadj, sums);
  hipLaunchKernelGGL(k_gemm_in, dim3(352, 6), dim3(256), 0, stream, x, projw, w1,
                     z, zT, zb, h1);
  hipLaunchKernelGGL(k_node, dim3(5632), dim3(256), 0, stream, x, z, h1, gw, gb,
                     b1, w2, b2, sq, wnode);
  hipLaunchKernelGGL(k_pass1, dim3(88, 16, 4), dim3(256), 0, stream, zT, sq, bm,
                     sums);
  hipLaunchKernelGGL(k_final, dim3(22, 22, 16), dim3(256), 0, stream, zb, sq,
                     wnode, bm, sums, chadj, thr, out);
}

// Round 5
// 976.222 us; speedup vs baseline: 2.1314x; 1.4136x over previous
//
#include <hip/hip_runtime.h>
#include <math.h>

typedef __attribute__((ext_vector_type(8))) short bf16x8;
typedef __attribute__((ext_vector_type(4))) float f32x4;

__device__ __forceinline__ float wsum64(float v) {
#pragma unroll
  for (int d = 32; d > 0; d >>= 1) v += __shfl_xor(v, d, 64);
  return v;
}

__device__ __forceinline__ unsigned short f2bf(float f) {
  unsigned u = __float_as_uint(f);
  u = (u + 0x7FFFu + ((u >> 16) & 1u)) >> 16;
  return (unsigned short)u;
}

// ---------------- K0: init (chadj extract + zero mean-sums) ----------------
__global__ void k_init(const float* __restrict__ smask, float* __restrict__ chadj,
                       double* __restrict__ sums) {
  int t = threadIdx.x;
  if (t < 4) sums[t] = 0.0;
  if (t < 484) {
    int c1 = t / 22, c2 = t % 22;
    chadj[t] = smask[(size_t)(c1 * 64) * 1408 + (size_t)c2 * 64];
  }
}

// ---------------- A: input GEMM: z (fp32 + bf16 + transposed) and h1-pre ----
__global__ __launch_bounds__(256) void k_gemm_in(
    const float* __restrict__ x, const float* __restrict__ projw,
    const float* __restrict__ w1, float* __restrict__ z, float* __restrict__ zT,
    unsigned short* __restrict__ zb, float* __restrict__ h1) {
  __shared__ float xs[16][68];
  __shared__ float wsT[16][68];
  __shared__ float ldsT[64][65];
  int n0 = blockIdx.x * 64;
  int o0 = blockIdx.y * 64;
  int tid = threadIdx.x;
  int tx = tid & 15, ty = tid >> 4;
  float acc[4][4];
#pragma unroll
  for (int i = 0; i < 4; i++)
#pragma unroll
    for (int j = 0; j < 4; j++) acc[i][j] = 0.f;
  for (int kc = 0; kc < 16; kc++) {
#pragma unroll
    for (int rep = 0; rep < 4; rep++) {
      int e = tid + rep * 256;
      int n = e >> 4, k = e & 15;
      xs[k][n] = x[(size_t)(n0 + n) * 256 + kc * 16 + k];
      int row = o0 + n;
      wsT[k][n] = (row < 256) ? projw[(size_t)row * 256 + kc * 16 + k]
                              : w1[(size_t)(row - 256) * 256 + kc * 16 + k];
    }
    __syncthreads();
#pragma unroll
    for (int k = 0; k < 16; k++) {
      float4 a4 = *(const float4*)&xs[k][4 * ty];
      float4 w4 = *(const float4*)&wsT[k][4 * tx];
      float ar[4] = {a4.x, a4.y, a4.z, a4.w};
      float wr[4] = {w4.x, w4.y, w4.z, w4.w};
#pragma unroll
      for (int i = 0; i < 4; i++)
#pragma unroll
        for (int j = 0; j < 4; j++) acc[i][j] = fmaf(ar[i], wr[j], acc[i][j]);
    }
    __syncthreads();
  }
  if (blockIdx.y >= 4) {
#pragma unroll
    for (int i = 0; i < 4; i++) {
      size_t base = (size_t)(n0 + 4 * ty + i) * 128 + (o0 - 256) + 4 * tx;
      float4 t;
      t.x = acc[i][0]; t.y = acc[i][1]; t.z = acc[i][2]; t.w = acc[i][3];
      *(float4*)&h1[base] = t;
    }
  } else {
#pragma unroll
    for (int i = 0; i < 4; i++) {
      size_t base = (size_t)(n0 + 4 * ty + i) * 256 + o0 + 4 * tx;
      float4 t;
      t.x = acc[i][0]; t.y = acc[i][1]; t.z = acc[i][2]; t.w = acc[i][3];
      *(float4*)&z[base] = t;
      unsigned lo = (unsigned)f2bf(acc[i][0]) | ((unsigned)f2bf(acc[i][1]) << 16);
      unsigned hi = (unsigned)f2bf(acc[i][2]) | ((unsigned)f2bf(acc[i][3]) << 16);
      uint2 u2; u2.x = lo; u2.y = hi;
      *(uint2*)(zb + base) = u2;
    }
    __syncthreads();
#pragma unroll
    for (int i = 0; i < 4; i++)
#pragma unroll
      for (int j = 0; j < 4; j++) ldsT[4 * tx + j][4 * ty + i] = acc[i][j];
    __syncthreads();
    int bblk = blockIdx.x / 22;
    int nbase = (blockIdx.x % 22) * 64;
#pragma unroll
    for (int rep = 0; rep < 16; rep++) {
      int e = tid + rep * 256;
      int oo = e >> 6, nn = e & 63;
      zT[(size_t)((bblk * 4 + blockIdx.y) * 64 + oo) * 1408 + nbase + nn] = ldsT[oo][nn];
    }
  }
}

// ---------------- B: per-node: sq per head, score (exact gelu), top-p gate --
__global__ __launch_bounds__(256) void k_node(
    const float* __restrict__ x, const float* __restrict__ z,
    const float* __restrict__ h1, const float* __restrict__ gw,
    const float* __restrict__ gb, const float* __restrict__ b1,
    const float* __restrict__ w2, const float* __restrict__ b2v,
    float* __restrict__ sq, float4* __restrict__ wnode) {
  int tid = threadIdx.x;
  int w = tid >> 6, lane = tid & 63;
  int node = blockIdx.x * 4 + w;
  int b = node / 1408, n = node % 1408;
  const float* zr = z + (size_t)node * 256;
  const float* xr = x + (size_t)node * 256;
#pragma unroll
  for (int c = 0; c < 4; c++) {
    float val = zr[c * 64 + lane];
    float s = wsum64(val * val);
    if (lane == 0) sq[(size_t)(b * 4 + c) * 1408 + n] = s;
  }
  float gl[3];
#pragma unroll
  for (int f = 0; f < 3; f++) {
    float p = 0.f;
#pragma unroll
    for (int c = 0; c < 4; c++)
      p = fmaf(xr[c * 64 + lane], gw[f * 256 + c * 64 + lane], p);
    gl[f] = wsum64(p) + gb[f];
  }
  const float* hr = h1 + (size_t)node * 128;
  float ps = 0.f;
#pragma unroll
  for (int c = 0; c < 2; c++) {
    float t = hr[c * 64 + lane] + b1[c * 64 + lane];
    float g = 0.5f * t * (1.f + erff(t * 0.7071067811865475f));
    ps = fmaf(g, w2[c * 64 + lane], ps);
  }
  float sc = wsum64(ps) + b2v[0];
  sc = 1.f / (1.f + expf(-sc));
  float mx = fmaxf(gl[0], fmaxf(gl[1], gl[2]));
  float ex[3];
  float esum = 0.f;
#pragma unroll
  for (int f = 0; f < 3; f++) { ex[f] = expf(gl[f] - mx); esum += ex[f]; }
  float p3[3];
#pragma unroll
  for (int f = 0; f < 3; f++) p3[f] = ex[f] / esum;
  int rk[3];
#pragma unroll
  for (int f = 0; f < 3; f++) {
    int r = 0;
#pragma unroll
    for (int g = 0; g < 3; g++)
      r += ((p3[g] > p3[f]) || (p3[g] == p3[f] && g < f)) ? 1 : 0;
    rk[f] = r;
  }
  float sp[3]; int oi[3];
#pragma unroll
  for (int f = 0; f < 3; f++) { sp[rk[f]] = p3[f]; oi[rk[f]] = f; }
  bool k1 = sp[0] < 0.85f;
  bool k2 = (sp[0] + sp[1]) < 0.85f;
  float wv[3];
  wv[oi[0]] = sp[0];
  wv[oi[1]] = k1 ? sp[1] : 0.f;
  wv[oi[2]] = k2 ? sp[2] : 0.f;
  float inv = 1.f / (wv[0] + wv[1] + wv[2] + 1e-8f);
  if (lane == 0) wnode[node] = make_float4(wv[0] * inv, wv[1] * inv, wv[2] * inv, sc);
}

// ---------------- P1: fp32 distances + exact top-k(211) select -> bitmap ----
// grid (88,16,4); block 256 = 4 waves. j split across waves: wave w owns
// tiles {w, w+4, ..., } of 64 j each (22 tiles total). Each B element feeds
// all 16 rows (4x less B traffic than row-split). Select: block-cooperative
// histogram per 4-row group; wave rr scans row rr (R4 scan verbatim).
__global__ __launch_bounds__(256, 2) void k_pass1(
    const float* __restrict__ zT, const float* __restrict__ sq,
    unsigned* __restrict__ bm, double* __restrict__ sums) {
  __shared__ float As[64][16];
  __shared__ float srowL[16];
  __shared__ unsigned hist[4][2112];
  __shared__ float cand[4][64];
  __shared__ unsigned candCnt[4];
  __shared__ int tbinS[4], rstarS[4];
  __shared__ float TS[4];
  int b = blockIdx.y, h = blockIdx.z;
  int i0 = blockIdx.x * 16;
  int tid = threadIdx.x;
  int w = tid >> 6, lane = tid & 63;
  const float* zTh = zT + (size_t)((b * 4 + h) * 64) * 1408;
  const float* sqh = sq + (size_t)(b * 4 + h) * 1408;
#pragma unroll
  for (int rep = 0; rep < 4; rep++) {
    int e = tid + rep * 256;
    int k = e >> 4, r = e & 15;
    As[k][r] = zTh[(size_t)k * 1408 + i0 + r];
  }
  if (tid < 16) srowL[tid] = sqh[i0 + tid];
  const int tc = (w < 2) ? 6 : 5;  // tiles per wave (22 = 6+6+5+5)
  // per-lane j base pointers and sq[j]
  const float* bp[6];
  float sqj[6];
#pragma unroll
  for (int t = 0; t < 6; t++) {
    int jb = (w + 4 * t) * 64 + lane;
    bp[t] = zTh + ((t < tc) ? jb : lane);
    sqj[t] = (t < tc) ? sqh[jb] : 0.f;
  }
  float v[16][6];
#pragma unroll
  for (int r = 0; r < 16; r++)
#pragma unroll
    for (int t = 0; t < 6; t++) v[r][t] = 0.f;
  __syncthreads();
  // K-loop: B scalar coalesced loads (prefetched), A broadcast from LDS
  float bc[6];
#pragma unroll
  for (int t = 0; t < 6; t++) bc[t] = bp[t][0];
  for (int k = 0; k < 64; k++) {
    float bn[6];
    if (k < 63) {
#pragma unroll
      for (int t = 0; t < 6; t++) bn[t] = bp[t][(size_t)(k + 1) * 1408];
    }
    float4 a0 = *(const float4*)&As[k][0];
    float4 a1 = *(const float4*)&As[k][4];
    float4 a2 = *(const float4*)&As[k][8];
    float4 a3 = *(const float4*)&As[k][12];
    float ar[16] = {a0.x, a0.y, a0.z, a0.w, a1.x, a1.y, a1.z, a1.w,
                    a2.x, a2.y, a2.z, a2.w, a3.x, a3.y, a3.z, a3.w};
#pragma unroll
    for (int r = 0; r < 16; r++)
#pragma unroll
      for (int t = 0; t < 6; t++) v[r][t] = fmaf(ar[r], bc[t], v[r][t]);
#pragma unroll
    for (int t = 0; t < 6; t++) bc[t] = bn[t];
  }
  // finalize: dot -> clamped d^2; invalid tile slots -> +inf
  float ssum = 0.f;
#pragma unroll
  for (int r = 0; r < 16; r++) {
    float sr = srowL[r];
#pragma unroll
    for (int t = 0; t < 6; t++) {
      float d = sr + sqj[t] - 2.f * v[r][t];
      d = fmaxf(d, 0.f);
      bool vld = (t < tc);
      if (vld) ssum += sqrtf(d);
      v[r][t] = vld ? d : INFINITY;
    }
  }
  // select: 4 groups of 4 rows; block-cooperative
  unsigned* histF = &hist[0][0];
#pragma unroll
  for (int g = 0; g < 4; g++) {
#pragma unroll
    for (int u = 0; u < 33; u++) histF[u * 256 + tid] = 0u;
    if (tid < 4) candCnt[tid] = 0u;
    __syncthreads();
    // fill (all threads, rows g*4..g*4+3)
#pragma unroll
    for (int rr = 0; rr < 4; rr++) {
#pragma unroll
      for (int t = 0; t < 6; t++) {
        if (t < tc) {
          float val = v[g * 4 + rr][t];
          unsigned key = (unsigned)fminf(val * 16.0f, 2047.0f);
          atomicAdd(&hist[rr][key + (key >> 5)], 1u);
        }
      }
    }
    __syncthreads();
    // scan: wave w handles row rr=w (R4 scan, conflict-free padded layout)
    {
      int rr = w;
      unsigned ssb = 0;
      int sbase = 33 * lane;
#pragma unroll
      for (int t = 0; t < 32; t++) ssb += hist[rr][sbase + t];
      unsigned inc = ssb;
#pragma unroll
      for (int d = 1; d < 64; d <<= 1) {
        unsigned u = __shfl_up(inc, d, 64);
        if (lane >= d) inc += u;
      }
      unsigned long long mk = __ballot(inc >= 211u);
      int Ls = __ffsll(mk) - 1;
      unsigned cbefore = (Ls > 0) ? (unsigned)__shfl((int)inc, Ls - 1, 64) : 0u;
      unsigned v2 = (lane < 32) ? hist[rr][33 * Ls + lane] : 0u;
      unsigned inc2 = v2;
#pragma unroll
      for (int d = 1; d < 32; d <<= 1) {
        unsigned u = __shfl_up(inc2, d, 64);
        if (lane >= d) inc2 += u;
      }
      bool c2 = (lane < 32) && (cbefore + inc2 >= 211u);
      mk = __ballot(c2);
      int is = __ffsll(mk) - 1;
      unsigned cbelow = cbefore + ((is > 0) ? (unsigned)__shfl((int)inc2, is - 1, 64) : 0u);
      if (lane == 0) {
        tbinS[rr] = Ls * 32 + is;
        rstarS[rr] = 211 - (int)cbelow;
      }
    }
    __syncthreads();
    // candidate collect (all threads)
#pragma unroll
    for (int rr = 0; rr < 4; rr++) {
      int tb = tbinS[rr];
#pragma unroll
      for (int t = 0; t < 6; t++) {
        if (t < tc) {
          float val = v[g * 4 + rr][t];
          unsigned key = (unsigned)fminf(val * 16.0f, 2047.0f);
          if ((int)key == tb) {
            unsigned id = atomicAdd(&candCnt[rr], 1u);
            if (id < 64u) cand[rr][id] = val;
          }
        }
      }
    }
    __syncthreads();
    // threshold: wave w ranks cand[w]
    {
      int rr = w;
      int rstar = rstarS[rr];
      unsigned craw = candCnt[rr];
      int cnt = (craw > 64u) ? 64 : (int)craw;
      float t2l = INFINITY;
      if (lane < cnt) {
        float xm = cand[rr][lane];
        int below = 0, eq = 0;
        for (int m = 0; m < cnt; m++) {
          float y = cand[rr][m];
          below += (y < xm) ? 1 : 0;
          eq += (y == xm) ? 1 : 0;
        }
        if (below < rstar && rstar <= below + eq) t2l = xm;
      }
#pragma unroll
      for (int dd = 32; dd > 0; dd >>= 1) t2l = fminf(t2l, __shfl_xor(t2l, dd, 64));
      if (lane == 0) TS[rr] = t2l;
    }
    __syncthreads();
    // bitmap: wave w writes its tiles' words (1 ballot = 1 tile of 64 j)
#pragma unroll
    for (int rr = 0; rr < 4; rr++) {
      float T = TS[rr];
      int row = i0 + g * 4 + rr;
      unsigned* bmrow = bm + (size_t)((h * 16 + b) * 1408 + row) * 44;
#pragma unroll
      for (int t = 0; t < 6; t++) {
        if (t < tc) {
          unsigned long long bl = __ballot(v[g * 4 + rr][t] <= T);
          int tile = w + 4 * t;
          if (lane == 0) bmrow[tile * 2] = (unsigned)bl;
          if (lane == 32) bmrow[tile * 2 + 1] = (unsigned)(bl >> 32);
        }
      }
    }
    __syncthreads();
  }
  ssum = wsum64(ssum);
  if (lane == 0) atomicAdd(&sums[h], (double)ssum);
}

// ---------------- E: bf16-MFMA recompute + fused epilogue -> out ------------
__global__ __launch_bounds__(256) void k_final(
    const unsigned short* __restrict__ zb, const float* __restrict__ sq,
    const float4* __restrict__ wnode, const unsigned* __restrict__ bm,
    const double* __restrict__ sums, const float* __restrict__ chadj,
    const float* __restrict__ thrp, float* __restrict__ out) {
  int it = blockIdx.x, jt = blockIdx.y, b = blockIdx.z;
  int tid = threadIdx.x, wv = tid >> 6, lane = tid & 63;
  int quad = lane >> 4, l15 = lane & 15;
  float c2h[4];
#pragma unroll
  for (int h = 0; h < 4; h++) {
    double mu = sums[h] * (1.0 / (16.0 * 1408.0 * 1408.0));
    c2h[h] = (float)(1.0 / (2.0 * mu * mu + 1e-8)) * 1.44269504088896f;
  }
  float thr = thrp[0];
  int ib = it * 64 + wv * 16;
  const unsigned short* za = zb + (size_t)(b * 1408 + ib + l15) * 256;
  bf16x8 af[4][2];
#pragma unroll
  for (int h = 0; h < 4; h++)
#pragma unroll
    for (int k0 = 0; k0 < 2; k0++)
      af[h][k0] = *(const bf16x8*)(za + h * 64 + k0 * 32 + quad * 8);
  int ibq = ib + quad * 4;
  float4 wi[4];
  float sqi[4][4];
#pragma unroll
  for (int reg = 0; reg < 4; reg++) {
    int i = ibq + reg;
    wi[reg] = wnode[b * 1408 + i];
#pragma unroll
    for (int h = 0; h < 4; h++) sqi[reg][h] = sq[(size_t)(b * 4 + h) * 1408 + i];
  }
#pragma unroll
  for (int js = 0; js < 4; js++) {
    int j = jt * 64 + js * 16 + l15;
    const unsigned short* zj = zb + (size_t)(b * 1408 + j) * 256;
    f32x4 acc[4];
#pragma unroll
    for (int h = 0; h < 4; h++) {
      bf16x8 b0 = *(const bf16x8*)(zj + h * 64 + quad * 8);
      bf16x8 b1f = *(const bf16x8*)(zj + h * 64 + 32 + quad * 8);
      f32x4 a = {0.f, 0.f, 0.f, 0.f};
      a = __builtin_amdgcn_mfma_f32_16x16x32_bf16(af[h][0], b0, a, 0, 0, 0);
      a = __builtin_amdgcn_mfma_f32_16x16x32_bf16(af[h][1], b1f, a, 0, 0, 0);
      acc[h] = a;
    }
    float sqj[4];
#pragma unroll
    for (int h = 0; h < 4; h++) sqj[h] = sq[(size_t)(b * 4 + h) * 1408 + j];
    float4 wj = wnode[b * 1408 + j];
    float adjv[4] = {0.f, 0.f, 0.f, 0.f};
#pragma unroll
    for (int h = 0; h < 4; h++) {
      const unsigned* bmh = bm + (size_t)(h * 16 + b) * 1408 * 44;
      unsigned wJ = bmh[(size_t)j * 44 + (ibq >> 5)];
#pragma unroll
      for (int reg = 0; reg < 4; reg++) {
        int i = ibq + reg;
        float d2 = sqi[reg][h] + sqj[h] - 2.f * acc[h][reg];
        d2 = fmaxf(d2, 0.f);
        float sim = exp2f(-d2 * c2h[h]);
        unsigned bi = bmh[(size_t)i * 44 + (j >> 5)] >> (j & 31);
        unsigned bj = wJ >> (i & 31);
        adjv[reg] += (((bi | bj) & 1u) != 0u) ? sim : 0.f;
      }
    }
#pragma unroll
    for (int reg = 0; reg < 4; reg++) {
      int i = ibq + reg;
      int chi = i >> 6, pi = i & 63, chj = j >> 6, pj = j & 63;
      float e0 = 0.5f * (wi[reg].x + wj.x);
      float e1 = 0.5f * (wi[reg].y + wj.y);
      float e2 = 0.5f * (wi[reg].z + wj.z);
      float a2 = 0.f;
      if (chi == chj) {
        int dp = pi - pj;
        if (dp == 1 || dp == -1) a2 += e0;
      }
      if (pi == pj && chadj[chi * 22 + chj] != 0.f) a2 += e1;
      float xw = (wi[reg].w * wj.w - thr) * 10.f;
      float pt = 1.f / (1.f + exp2f(-xw * 1.44269504088896f));
      a2 += pt * e2;
      out[(size_t)(b * 1408 + i) * 1408 + j] = 0.25f * adjv[reg] * a2;
    }
  }
}

// ---------------------------------------------------------------------------
extern "C" void kernel_launch(void* const* d_in, const int* in_sizes, int n_in,
                              void* d_out, int out_size, void* d_ws, size_t ws_size,
                              hipStream_t stream) {
  (void)in_sizes; (void)n_in; (void)out_size; (void)ws_size;
  const float* x = (const float*)d_in[0];
  const float* projw = (const float*)d_in[1];
  const float* gw = (const float*)d_in[2];
  const float* gb = (const float*)d_in[3];
  const float* w1 = (const float*)d_in[4];
  const float* b1 = (const float*)d_in[5];
  const float* w2 = (const float*)d_in[6];
  const float* b2 = (const float*)d_in[7];
  const float* thr = (const float*)d_in[8];
  const float* smask = (const float*)d_in[10];
  float* out = (float*)d_out;
  char* ws = (char*)d_ws;
  size_t off = 0;
  auto take = [&](size_t bytes) {
    char* p = ws + off;
    off += (bytes + 255) & ~(size_t)255;
    return p;
  };
  float* z = (float*)take((size_t)22528 * 256 * 4);
  float* zT = (float*)take((size_t)22528 * 256 * 4);
  unsigned short* zb = (unsigned short*)take((size_t)22528 * 256 * 2);
  float* h1 = (float*)take((size_t)22528 * 128 * 4);
  float* sq = (float*)take((size_t)16 * 4 * 1408 * 4);
  float4* wnode = (float4*)take((size_t)22528 * 16);
  unsigned* bm = (unsigned*)take((size_t)4 * 16 * 1408 * 44 * 4);
  float* chadj = (float*)take(484 * 4);
  double* sums = (double*)take(4 * 8);

  hipLaunchKernelGGL(k_init, dim3(1), dim3(512), 0, stream, smask, chadj, sums);
  hipLaunchKernelGGL(k_gemm_in, dim3(352, 6), dim3(256), 0, stream, x, projw, w1,
                     z, zT, zb, h1);
  hipLaunchKernelGGL(k_node, dim3(5632), dim3(256), 0, stream, x, z, h1, gw, gb,
                     b1, w2, b2, sq, wnode);
  hipLaunchKernelGGL(k_pass1, dim3(88, 16, 4), dim3(256), 0, stream, zT, sq, bm,
                     sums);
  hipLaunchKernelGGL(k_final, dim3(22, 22, 16), dim3(256), 0, stream, zb, sq,
                     wnode, bm, sums, chadj, thr, out);
}